// Round 2
// baseline (345.415 us; speedup 1.0000x reference)
//
#include <hip/hip_runtime.h>
#include <stdint.h>

#define S_LEN 2048
#define DIMM  2048
#define NH    16
#define NKV   2

typedef __attribute__((ext_vector_type(8))) short s16x8;
typedef __attribute__((ext_vector_type(8))) unsigned short u16x8;
typedef __attribute__((ext_vector_type(4))) float f32x4;

__device__ __forceinline__ unsigned short f2bf(float f){
  unsigned int u = __builtin_bit_cast(unsigned int, f);
  u += 0x7fffu + ((u >> 16) & 1u);
  return (unsigned short)(u >> 16);
}

__device__ __forceinline__ void gload16(const void* g, void* l){
  __builtin_amdgcn_global_load_lds(
      (const __attribute__((address_space(1))) unsigned int*)g,
      (__attribute__((address_space(3))) unsigned int*)l, 16, 0, 0);
}

// ---------------- fp32 -> bf16 convert ----------------
__global__ __launch_bounds__(256) void cvt_bf16(const float* __restrict__ src,
                                                unsigned short* __restrict__ dst, int n){
  int i = (blockIdx.x * 256 + threadIdx.x) * 8;
  if (i >= n) return;
  const float4* s4 = (const float4*)(src + i);
  float4 a = s4[0], b = s4[1];
  u16x8 o;
  o[0]=f2bf(a.x); o[1]=f2bf(a.y); o[2]=f2bf(a.z); o[3]=f2bf(a.w);
  o[4]=f2bf(b.x); o[5]=f2bf(b.y); o[6]=f2bf(b.z); o[7]=f2bf(b.w);
  *(u16x8*)(dst + i) = o;
}

// ---------------- C = A(bf16,[M,K]) @ W(bf16,[N,K])^T -> fp32 [M,N] ----------------
__global__ __launch_bounds__(256) void gemm_bt(const unsigned short* __restrict__ A,
                                               const unsigned short* __restrict__ W,
                                               float* __restrict__ C,
                                               int M, int N, int K){
  __shared__ __attribute__((aligned(16))) unsigned short As[128*64];
  __shared__ __attribute__((aligned(16))) unsigned short Bs[128*64];
  const int t = threadIdx.x;
  const int lane = t & 63, wave = t >> 6;
  const int l15 = lane & 15, g = lane >> 4;
  const int m0 = blockIdx.y * 128, n0 = blockIdx.x * 128;
  const int wm = (wave >> 1) * 64, wn = (wave & 1) * 64;
  const int srow = t >> 3, sdblk = t & 7;
  const long ldsoff = (long)(t >> 6) * 1024;
  f32x4 acc[4][4] = {};
  for (int k0 = 0; k0 < K; k0 += 64){
    __syncthreads();
    #pragma unroll
    for (int r = 0; r < 4; ++r){
      int row = r*32 + srow;
      int db  = sdblk ^ (row & 7);
      gload16(A + (long)(m0+row)*K + k0 + db*8, (char*)As + r*4096 + ldsoff);
    }
    #pragma unroll
    for (int r = 0; r < 4; ++r){
      int row = r*32 + srow;
      int db  = sdblk ^ (row & 7);
      gload16(W + (long)(n0+row)*K + k0 + db*8, (char*)Bs + r*4096 + ldsoff);
    }
    __syncthreads();
    s16x8 af[4][2], bfr[4][2];
    #pragma unroll
    for (int mi = 0; mi < 4; ++mi)
      #pragma unroll
      for (int kc = 0; kc < 2; ++kc){
        int row = wm + mi*16 + l15;
        int db = (kc*4 + g) ^ (row & 7);
        af[mi][kc] = *(const s16x8*)(As + row*64 + db*8);
      }
    #pragma unroll
    for (int ni = 0; ni < 4; ++ni)
      #pragma unroll
      for (int kc = 0; kc < 2; ++kc){
        int row = wn + ni*16 + l15;
        int db = (kc*4 + g) ^ (row & 7);
        bfr[ni][kc] = *(const s16x8*)(Bs + row*64 + db*8);
      }
    #pragma unroll
    for (int mi = 0; mi < 4; ++mi)
      #pragma unroll
      for (int ni = 0; ni < 4; ++ni)
        #pragma unroll
        for (int kc = 0; kc < 2; ++kc)
          acc[mi][ni] = __builtin_amdgcn_mfma_f32_16x16x32_bf16(af[mi][kc], bfr[ni][kc], acc[mi][ni], 0, 0, 0);
  }
  #pragma unroll
  for (int mi = 0; mi < 4; ++mi)
    #pragma unroll
    for (int ni = 0; ni < 4; ++ni)
      #pragma unroll
      for (int rg = 0; rg < 4; ++rg){
        int row = m0 + wm + mi*16 + g*4 + rg;
        int col = n0 + wn + ni*16 + l15;
        C[(long)row*N + col] = acc[mi][ni][rg];
      }
}

// ---------------- RMSNorm + rotary for Q and K ----------------
__global__ __launch_bounds__(256) void normrope(const float* __restrict__ qkv,
    const float* __restrict__ cosb, const float* __restrict__ sinb,
    const float* __restrict__ qg, const float* __restrict__ kg,
    unsigned short* __restrict__ q_attn, unsigned short* __restrict__ k_attn){
  int wave = threadIdx.x >> 6, lane = threadIdx.x & 63;
  int rid = blockIdx.x * 4 + wave;
  int d0 = lane * 2;
  const float* src; unsigned short* dst; const float* gm; float sc; int s;
  if (rid < 2*S_LEN*NH){
    int bs = rid >> 4, h = rid & 15;
    int b = bs >> 11; s = bs & 2047;
    src = qkv + (long)bs*2560 + h*128;
    dst = q_attn + ((long)(b*NH + h)*S_LEN + s)*128;
    gm = qg; sc = 0.08838834764831845f;  // 1/sqrt(128)
  } else {
    int r2 = rid - 2*S_LEN*NH;
    int bs = r2 >> 1, kv = r2 & 1;
    int b = bs >> 11; s = bs & 2047;
    src = qkv + (long)bs*2560 + 2048 + kv*128;
    dst = k_attn + ((long)(b*NKV + kv)*S_LEN + s)*128;
    gm = kg; sc = 1.0f;
  }
  float2 x = *(const float2*)(src + d0);
  float ss = x.x*x.x + x.y*x.y;
  #pragma unroll
  for (int m = 1; m < 64; m <<= 1) ss += __shfl_xor(ss, m);
  float r = rsqrtf(ss * (1.0f/128.0f) + 1e-6f);
  float2 gv = *(const float2*)(gm + d0);
  float n0 = x.x * r * gv.x, n1 = x.y * r * gv.y;
  float p0 = __shfl_xor(n0, 32), p1 = __shfl_xor(n1, 32);
  float sgn = (d0 < 64) ? -1.f : 1.f;
  float2 c  = *(const float2*)(cosb + (long)s*128 + d0);
  float2 sn = *(const float2*)(sinb + (long)s*128 + d0);
  float o0 = (n0*c.x + sgn*p0*sn.x) * sc;
  float o1 = (n1*c.y + sgn*p1*sn.y) * sc;
  unsigned int pk = (unsigned int)f2bf(o0) | ((unsigned int)f2bf(o1) << 16);
  *(unsigned int*)(dst + d0) = pk;
}

// ---------------- V: [B,S,KV,128] cols of qkv -> bf16 [B,KV,128,S] (transposed) ----------------
__global__ __launch_bounds__(256) void vtrans(const float* __restrict__ qkv,
                                              unsigned short* __restrict__ v_t){
  __shared__ __attribute__((aligned(16))) unsigned short lds[128*72];
  int bid = blockIdx.x;
  int s0 = (bid & 31) * 64;
  int kv = (bid >> 5) & 1;
  int b  = bid >> 6;
  int t = threadIdx.x;
  #pragma unroll
  for (int it = 0; it < 32; ++it){
    int idx = it*256 + t;
    int s = idx >> 7, d = idx & 127;
    float v = qkv[(long)(b*S_LEN + s0 + s)*2560 + 2304 + kv*128 + d];
    lds[d*72 + s] = f2bf(v);
  }
  __syncthreads();
  #pragma unroll
  for (int it = 0; it < 4; ++it){
    int c = it*256 + t;
    int d = c >> 3, s8 = c & 7;
    u16x8 vv = *(const u16x8*)(lds + d*72 + s8*8);
    *(u16x8*)(v_t + ((long)(b*NKV + kv)*128 + d)*S_LEN + s0 + s8*8) = vv;
  }
}

// ---------------- flash attention ----------------
// grid: 32(qt, descending LPT) x 32(b,h); block 256 = 4 waves x 16 q-rows. KVB=64.
// K staged in LDS (XOR-swizzled); V read direct from global (L2-resident, 512KB/(b,kvh));
// P transposed through per-wave private LDS (stride 68 => conflict-free).
__global__ __launch_bounds__(256) void attn_fwd(const unsigned short* __restrict__ q_attn,
    const unsigned short* __restrict__ k_attn, const unsigned short* __restrict__ v_t,
    unsigned short* __restrict__ attn_out, const int* __restrict__ pp){
  __shared__ __attribute__((aligned(16))) unsigned short Ks[64*128];
  __shared__ __attribute__((aligned(16))) unsigned short Ps[4][16*68];
  const int p = pp[0];
  int bid = blockIdx.x;
  int qt = 31 - (bid >> 5);          // LPT: longest blocks dispatch first
  int bh = bid & 31;
  int h = bh & 15, b = bh >> 4;
  int kvh = h >> 3;
  int t = threadIdx.x, wave = t >> 6, lane = t & 63;
  int l15 = lane & 15, g = lane >> 4;
  int qs = qt * 64;
  int qrb = qs + wave*16;
  const unsigned short* qb = q_attn + ((long)(b*NH + h)*S_LEN + qrb + l15)*128;
  s16x8 qf[4];
  #pragma unroll
  for (int kc = 0; kc < 4; ++kc) qf[kc] = *(const s16x8*)(qb + g*8 + kc*32);
  f32x4 O[8] = {};
  float mr[4] = {-3e38f,-3e38f,-3e38f,-3e38f};
  float lr[4] = {0.f,0.f,0.f,0.f};
  int kv_end = (qs < p) ? ((p > qs+64) ? p : qs+64) : (qs+64);
  const unsigned short* kb0 = k_attn + ((long)(b*NKV + kvh)*S_LEN)*128;
  const unsigned short* vb0 = v_t + ((long)(b*NKV + kvh)*128)*S_LEN;
  const int srow16 = t >> 4, sd16 = t & 15;
  const long ldsoff = (long)(t >> 6) * 1024;

  for (int j0 = 0; j0 < kv_end; j0 += 64){
    __syncthreads();   // all QK reads of Ks done before restage
    #pragma unroll
    for (int r = 0; r < 4; ++r){
      int j = r*16 + srow16;
      int db = sd16 ^ (j & 7);
      gload16(kb0 + (long)(j0 + j)*128 + db*8, (char*)Ks + r*4096 + ldsoff);
    }
    __syncthreads();   // staging complete
    // QK^T (scale pre-folded into Q)
    f32x4 sa[4] = {};
    __builtin_amdgcn_s_setprio(1);
    #pragma unroll
    for (int nt = 0; nt < 4; ++nt){
      int krow = nt*16 + l15;
      #pragma unroll
      for (int kc = 0; kc < 4; ++kc){
        int db = (kc*4 + g) ^ (krow & 7);
        s16x8 kf = *(const s16x8*)(Ks + krow*128 + db*8);
        sa[nt] = __builtin_amdgcn_mfma_f32_16x16x32_bf16(qf[kc], kf, sa[nt], 0, 0, 0);
      }
    }
    __builtin_amdgcn_s_setprio(0);
    // mask (skipped on wave-uniform fully-valid tiles) + per-row max
    float tm[4] = {-3e38f,-3e38f,-3e38f,-3e38f};
    bool full = (j0 + 63 <= qrb) || ((qrb + 15 < p) && (j0 + 63 < p));
    if (full){
      #pragma unroll
      for (int nt = 0; nt < 4; ++nt)
        #pragma unroll
        for (int rg = 0; rg < 4; ++rg) tm[rg] = fmaxf(tm[rg], sa[nt][rg]);
    } else {
      #pragma unroll
      for (int nt = 0; nt < 4; ++nt)
        #pragma unroll
        for (int rg = 0; rg < 4; ++rg){
          int i = qrb + g*4 + rg;
          int j = j0 + nt*16 + l15;
          bool ok = (j <= i) || ((i < p) && (j < p));
          float sv = ok ? sa[nt][rg] : -3e38f;
          sa[nt][rg] = sv;
          tm[rg] = fmaxf(tm[rg], sv);
        }
    }
    #pragma unroll
    for (int mk = 1; mk <= 8; mk <<= 1)
      #pragma unroll
      for (int rg = 0; rg < 4; ++rg) tm[rg] = fmaxf(tm[rg], __shfl_xor(tm[rg], mk));
    // online softmax update
    float sf[4];
    #pragma unroll
    for (int rg = 0; rg < 4; ++rg){
      float nm = fmaxf(mr[rg], tm[rg]);
      sf[rg] = __expf(mr[rg] - nm);
      mr[rg] = nm;
    }
    #pragma unroll
    for (int dt = 0; dt < 8; ++dt)
      #pragma unroll
      for (int rg = 0; rg < 4; ++rg) O[dt][rg] *= sf[rg];
    float rs[4] = {0.f,0.f,0.f,0.f};
    #pragma unroll
    for (int nt = 0; nt < 4; ++nt)
      #pragma unroll
      for (int rg = 0; rg < 4; ++rg){
        float e = __expf(sa[nt][rg] - mr[rg]);
        sa[nt][rg] = e;
        rs[rg] += e;
      }
    #pragma unroll
    for (int mk = 1; mk <= 8; mk <<= 1)
      #pragma unroll
      for (int rg = 0; rg < 4; ++rg) rs[rg] += __shfl_xor(rs[rg], mk);
    #pragma unroll
    for (int rg = 0; rg < 4; ++rg) lr[rg] = lr[rg]*sf[rg] + rs[rg];
    // P -> per-wave private LDS (stride 68: conflict-free), no barrier needed
    unsigned short* ps = &Ps[wave][0];
    #pragma unroll
    for (int nt = 0; nt < 4; ++nt)
      #pragma unroll
      for (int rg = 0; rg < 4; ++rg)
        ps[(g*4+rg)*68 + nt*16 + l15] = f2bf(sa[nt][rg]);
    s16x8 pf[2];
    #pragma unroll
    for (int kc = 0; kc < 2; ++kc) pf[kc] = *(const s16x8*)(ps + l15*68 + kc*32 + g*8);
    // PV: V fragments direct from global (L2)
    __builtin_amdgcn_s_setprio(1);
    #pragma unroll
    for (int dt = 0; dt < 8; ++dt){
      int d = dt*16 + l15;
      const unsigned short* vrow = vb0 + (long)d*S_LEN + j0;
      #pragma unroll
      for (int kc = 0; kc < 2; ++kc){
        s16x8 vf = *(const s16x8*)(vrow + (kc*4+g)*8);
        O[dt] = __builtin_amdgcn_mfma_f32_16x16x32_bf16(pf[kc], vf, O[dt], 0, 0, 0);
      }
    }
    __builtin_amdgcn_s_setprio(0);
  }
  float inv[4];
  #pragma unroll
  for (int rg = 0; rg < 4; ++rg) inv[rg] = 1.0f / lr[rg];
  #pragma unroll
  for (int dt = 0; dt < 8; ++dt)
    #pragma unroll
    for (int rg = 0; rg < 4; ++rg){
      int row = qrb + g*4 + rg;
      int col = h*128 + dt*16 + l15;
      attn_out[(long)(b*S_LEN + row)*DIMM + col] = f2bf(O[dt][rg]*inv[rg]);
    }
}

extern "C" void kernel_launch(void* const* d_in, const int* in_sizes, int n_in,
                              void* d_out, int out_size, void* d_ws, size_t ws_size,
                              hipStream_t stream){
  const float* x    = (const float*)d_in[0];
  const float* cosb = (const float*)d_in[1];
  const float* sinb = (const float*)d_in[2];
  const float* wq   = (const float*)d_in[3];
  const float* wk   = (const float*)d_in[4];
  const float* wv   = (const float*)d_in[5];
  const float* wo   = (const float*)d_in[6];
  const float* qg   = (const float*)d_in[7];
  const float* kg   = (const float*)d_in[8];
  const int*   pp   = (const int*)d_in[9];

  char* ws = (char*)d_ws;
  unsigned short* xb    = (unsigned short*)(ws);                 // 4096x2048 bf16
  unsigned short* wqkvb = (unsigned short*)(ws + 16777216);      // 2560x2048 bf16
  unsigned short* wob   = (unsigned short*)(ws + 27262976);      // 2048x2048 bf16
  float*          qkv   = (float*)(ws + 35651584);               // 4096x2560 f32
  unsigned short* qat   = (unsigned short*)(ws + 77594624);      // [B,16,S,128]
  unsigned short* kat   = (unsigned short*)(ws + 94371840);      // [B,2,S,128]
  unsigned short* vt    = (unsigned short*)(ws + 96468992);      // [B,2,128,S]
  unsigned short* aout  = (unsigned short*)(ws + 98566144);      // [B,S,2048]

  cvt_bf16<<<8388608/2048, 256, 0, stream>>>(x,  xb, 8388608);
  cvt_bf16<<<4194304/2048, 256, 0, stream>>>(wq, wqkvb, 4194304);
  cvt_bf16<<< 524288/2048, 256, 0, stream>>>(wk, wqkvb + 4194304, 524288);
  cvt_bf16<<< 524288/2048, 256, 0, stream>>>(wv, wqkvb + 4718592, 524288);
  cvt_bf16<<<4194304/2048, 256, 0, stream>>>(wo, wob, 4194304);

  gemm_bt<<<dim3(2560/128, 4096/128), 256, 0, stream>>>(xb, wqkvb, qkv, 4096, 2560, 2048);
  normrope<<<73728/4, 256, 0, stream>>>(qkv, cosb, sinb, qg, kg, qat, kat);
  vtrans<<<128, 256, 0, stream>>>(qkv, vt);
  attn_fwd<<<1024, 256, 0, stream>>>(qat, kat, vt, aout, pp);
  gemm_bt<<<dim3(2048/128, 4096/128), 256, 0, stream>>>(aout, wob, (float*)d_out, 4096, 2048, 2048);
}

// Round 3
// 305.089 us; speedup vs baseline: 1.1322x; 1.1322x over previous
//
#include <hip/hip_runtime.h>
#include <stdint.h>

#define S_LEN 2048
#define DIMM  2048
#define NH    16
#define NKV   2

typedef __attribute__((ext_vector_type(8))) short s16x8;
typedef __attribute__((ext_vector_type(8))) unsigned short u16x8;
typedef __attribute__((ext_vector_type(4))) float f32x4;

__device__ __forceinline__ unsigned short f2bf(float f){
  unsigned int u = __builtin_bit_cast(unsigned int, f);
  u += 0x7fffu + ((u >> 16) & 1u);
  return (unsigned short)(u >> 16);
}

__device__ __forceinline__ void gload16(const void* g, void* l){
  __builtin_amdgcn_global_load_lds(
      (const __attribute__((address_space(1))) unsigned int*)g,
      (__attribute__((address_space(3))) unsigned int*)l, 16, 0, 0);
}

// ---------------- fp32 -> bf16 convert ----------------
__global__ __launch_bounds__(256) void cvt_bf16(const float* __restrict__ src,
                                                unsigned short* __restrict__ dst, int n){
  int i = (blockIdx.x * 256 + threadIdx.x) * 8;
  if (i >= n) return;
  const float4* s4 = (const float4*)(src + i);
  float4 a = s4[0], b = s4[1];
  u16x8 o;
  o[0]=f2bf(a.x); o[1]=f2bf(a.y); o[2]=f2bf(a.z); o[3]=f2bf(a.w);
  o[4]=f2bf(b.x); o[5]=f2bf(b.y); o[6]=f2bf(b.z); o[7]=f2bf(b.w);
  *(u16x8*)(dst + i) = o;
}

// ---------------- C = A(bf16,[M,K]) @ W(bf16,[N,K])^T -> fp32 [M,N] ----------------
__global__ __launch_bounds__(256) void gemm_bt(const unsigned short* __restrict__ A,
                                               const unsigned short* __restrict__ W,
                                               float* __restrict__ C,
                                               int M, int N, int K){
  __shared__ __attribute__((aligned(16))) unsigned short As[128*64];
  __shared__ __attribute__((aligned(16))) unsigned short Bs[128*64];
  const int t = threadIdx.x;
  const int lane = t & 63, wave = t >> 6;
  const int l15 = lane & 15, g = lane >> 4;
  const int m0 = blockIdx.y * 128, n0 = blockIdx.x * 128;
  const int wm = (wave >> 1) * 64, wn = (wave & 1) * 64;
  const int srow = t >> 3, sdblk = t & 7;
  const long ldsoff = (long)(t >> 6) * 1024;
  f32x4 acc[4][4] = {};
  for (int k0 = 0; k0 < K; k0 += 64){
    __syncthreads();
    #pragma unroll
    for (int r = 0; r < 4; ++r){
      int row = r*32 + srow;
      int db  = sdblk ^ (row & 7);
      gload16(A + (long)(m0+row)*K + k0 + db*8, (char*)As + r*4096 + ldsoff);
    }
    #pragma unroll
    for (int r = 0; r < 4; ++r){
      int row = r*32 + srow;
      int db  = sdblk ^ (row & 7);
      gload16(W + (long)(n0+row)*K + k0 + db*8, (char*)Bs + r*4096 + ldsoff);
    }
    __syncthreads();
    s16x8 af[4][2], bfr[4][2];
    #pragma unroll
    for (int mi = 0; mi < 4; ++mi)
      #pragma unroll
      for (int kc = 0; kc < 2; ++kc){
        int row = wm + mi*16 + l15;
        int db = (kc*4 + g) ^ (row & 7);
        af[mi][kc] = *(const s16x8*)(As + row*64 + db*8);
      }
    #pragma unroll
    for (int ni = 0; ni < 4; ++ni)
      #pragma unroll
      for (int kc = 0; kc < 2; ++kc){
        int row = wn + ni*16 + l15;
        int db = (kc*4 + g) ^ (row & 7);
        bfr[ni][kc] = *(const s16x8*)(Bs + row*64 + db*8);
      }
    #pragma unroll
    for (int mi = 0; mi < 4; ++mi)
      #pragma unroll
      for (int ni = 0; ni < 4; ++ni)
        #pragma unroll
        for (int kc = 0; kc < 2; ++kc)
          acc[mi][ni] = __builtin_amdgcn_mfma_f32_16x16x32_bf16(af[mi][kc], bfr[ni][kc], acc[mi][ni], 0, 0, 0);
  }
  #pragma unroll
  for (int mi = 0; mi < 4; ++mi)
    #pragma unroll
    for (int ni = 0; ni < 4; ++ni)
      #pragma unroll
      for (int rg = 0; rg < 4; ++rg){
        int row = m0 + wm + mi*16 + g*4 + rg;
        int col = n0 + wn + ni*16 + l15;
        C[(long)row*N + col] = acc[mi][ni][rg];
      }
}

// ---------------- RMSNorm + rotary for Q and K ----------------
__global__ __launch_bounds__(256) void normrope(const float* __restrict__ qkv,
    const float* __restrict__ cosb, const float* __restrict__ sinb,
    const float* __restrict__ qg, const float* __restrict__ kg,
    unsigned short* __restrict__ q_attn, unsigned short* __restrict__ k_attn){
  int wave = threadIdx.x >> 6, lane = threadIdx.x & 63;
  int rid = blockIdx.x * 4 + wave;
  int d0 = lane * 2;
  const float* src; unsigned short* dst; const float* gm; float sc; int s;
  if (rid < 2*S_LEN*NH){
    int bs = rid >> 4, h = rid & 15;
    int b = bs >> 11; s = bs & 2047;
    src = qkv + (long)bs*2560 + h*128;
    dst = q_attn + ((long)(b*NH + h)*S_LEN + s)*128;
    gm = qg; sc = 0.08838834764831845f;  // 1/sqrt(128)
  } else {
    int r2 = rid - 2*S_LEN*NH;
    int bs = r2 >> 1, kv = r2 & 1;
    int b = bs >> 11; s = bs & 2047;
    src = qkv + (long)bs*2560 + 2048 + kv*128;
    dst = k_attn + ((long)(b*NKV + kv)*S_LEN + s)*128;
    gm = kg; sc = 1.0f;
  }
  float2 x = *(const float2*)(src + d0);
  float ss = x.x*x.x + x.y*x.y;
  #pragma unroll
  for (int m = 1; m < 64; m <<= 1) ss += __shfl_xor(ss, m);
  float r = rsqrtf(ss * (1.0f/128.0f) + 1e-6f);
  float2 gv = *(const float2*)(gm + d0);
  float n0 = x.x * r * gv.x, n1 = x.y * r * gv.y;
  float p0 = __shfl_xor(n0, 32), p1 = __shfl_xor(n1, 32);
  float sgn = (d0 < 64) ? -1.f : 1.f;
  float2 c  = *(const float2*)(cosb + (long)s*128 + d0);
  float2 sn = *(const float2*)(sinb + (long)s*128 + d0);
  float o0 = (n0*c.x + sgn*p0*sn.x) * sc;
  float o1 = (n1*c.y + sgn*p1*sn.y) * sc;
  unsigned int pk = (unsigned int)f2bf(o0) | ((unsigned int)f2bf(o1) << 16);
  *(unsigned int*)(dst + d0) = pk;
}

// ---------------- V: [B,S,KV,128] cols of qkv -> bf16 [B,KV,128,S] (transposed) ----------------
__global__ __launch_bounds__(256) void vtrans(const float* __restrict__ qkv,
                                              unsigned short* __restrict__ v_t){
  __shared__ __attribute__((aligned(16))) unsigned short lds[128*72];
  int bid = blockIdx.x;
  int s0 = (bid & 31) * 64;
  int kv = (bid >> 5) & 1;
  int b  = bid >> 6;
  int t = threadIdx.x;
  #pragma unroll
  for (int it = 0; it < 32; ++it){
    int idx = it*256 + t;
    int s = idx >> 7, d = idx & 127;
    float v = qkv[(long)(b*S_LEN + s0 + s)*2560 + 2304 + kv*128 + d];
    lds[d*72 + s] = f2bf(v);
  }
  __syncthreads();
  #pragma unroll
  for (int it = 0; it < 4; ++it){
    int c = it*256 + t;
    int d = c >> 3, s8 = c & 7;
    u16x8 vv = *(const u16x8*)(lds + d*72 + s8*8);
    *(u16x8*)(v_t + ((long)(b*NKV + kv)*128 + d)*S_LEN + s0 + s8*8) = vv;
  }
}

// ---------------- flash attention ----------------
// grid: 32(qt, LPT desc) x 32(b,h); block 256 = 4 waves x 16 q-rows. KVB=64.
// K double-buffered in LDS via global_load_lds (stage t+1 issued before compute t,
// single barrier per tile => stage latency hidden under tile body).
// V^T fragments prefetched into registers at tile top (L2 latency hidden under QK+softmax).
__global__ __launch_bounds__(256) void attn_fwd(const unsigned short* __restrict__ q_attn,
    const unsigned short* __restrict__ k_attn, const unsigned short* __restrict__ v_t,
    unsigned short* __restrict__ attn_out, const int* __restrict__ pp){
  __shared__ __attribute__((aligned(16))) unsigned short Ks[2][64*128];
  __shared__ __attribute__((aligned(16))) unsigned short Ps[4][16*68];
  const int p = pp[0];
  int bid = blockIdx.x;
  int qt = 31 - (bid >> 5);          // LPT: longest blocks dispatch first
  int bh = bid & 31;
  int h = bh & 15, b = bh >> 4;
  int kvh = h >> 3;
  int t = threadIdx.x, wave = t >> 6, lane = t & 63;
  int l15 = lane & 15, g = lane >> 4;
  int qs = qt * 64;
  int qrb = qs + wave*16;
  const unsigned short* qb = q_attn + ((long)(b*NH + h)*S_LEN + qrb + l15)*128;
  s16x8 qf[4];
  #pragma unroll
  for (int kc = 0; kc < 4; ++kc) qf[kc] = *(const s16x8*)(qb + g*8 + kc*32);
  f32x4 O[8] = {};
  float mr[4] = {-3e38f,-3e38f,-3e38f,-3e38f};
  float lr[4] = {0.f,0.f,0.f,0.f};
  int kv_end = (qs < p) ? ((p > qs+64) ? p : qs+64) : (qs+64);
  const unsigned short* kb0 = k_attn + ((long)(b*NKV + kvh)*S_LEN)*128;
  const unsigned short* vb0 = v_t + ((long)(b*NKV + kvh)*128)*S_LEN;
  const int srow16 = t >> 4, sd16 = t & 15;
  const long ldsoff = (long)wave * 1024;
  // lane-personal V^T base: row (dt*16 + l15), element offset g*8 within j-run
  const unsigned short* vbase = vb0 + (long)l15*S_LEN + g*8;

  // prologue: stage tile 0 into Ks[0]
  #pragma unroll
  for (int r = 0; r < 4; ++r){
    int j = r*16 + srow16;
    int db = sd16 ^ (j & 7);
    gload16(kb0 + (long)j*128 + db*8, (char*)Ks[0] + r*4096 + ldsoff);
  }
  __syncthreads();
  int cur = 0;

  for (int j0 = 0; j0 < kv_end; j0 += 64){
    // V prefetch into registers (independent of K stage; consumed ~700cyc later)
    s16x8 vf[8][2];
    #pragma unroll
    for (int dt = 0; dt < 8; ++dt)
      #pragma unroll
      for (int kc = 0; kc < 2; ++kc)
        vf[dt][kc] = *(const s16x8*)(vbase + (long)dt*16*S_LEN + j0 + kc*32);
    // stage NEXT K tile into the other buffer (drains at the bottom barrier)
    if (j0 + 64 < kv_end){
      const unsigned short* kb = kb0 + (long)(j0 + 64)*128;
      char* dst = (char*)Ks[cur^1] + ldsoff;
      #pragma unroll
      for (int r = 0; r < 4; ++r){
        int j = r*16 + srow16;
        int db = sd16 ^ (j & 7);
        gload16(kb + (long)j*128 + db*8, dst + r*4096);
      }
    }
    // QK^T from Ks[cur] (scale pre-folded into Q)
    const unsigned short* ksc = Ks[cur];
    f32x4 sa[4] = {};
    __builtin_amdgcn_s_setprio(1);
    #pragma unroll
    for (int nt = 0; nt < 4; ++nt){
      int krow = nt*16 + l15;
      #pragma unroll
      for (int kc = 0; kc < 4; ++kc){
        int db = (kc*4 + g) ^ (krow & 7);
        s16x8 kf = *(const s16x8*)(ksc + krow*128 + db*8);
        sa[nt] = __builtin_amdgcn_mfma_f32_16x16x32_bf16(qf[kc], kf, sa[nt], 0, 0, 0);
      }
    }
    __builtin_amdgcn_s_setprio(0);
    // mask (skipped on wave-uniform fully-valid tiles) + per-row max
    float tm[4] = {-3e38f,-3e38f,-3e38f,-3e38f};
    bool full = (j0 + 63 <= qrb) || ((qrb + 15 < p) && (j0 + 63 < p));
    if (full){
      #pragma unroll
      for (int nt = 0; nt < 4; ++nt)
        #pragma unroll
        for (int rg = 0; rg < 4; ++rg) tm[rg] = fmaxf(tm[rg], sa[nt][rg]);
    } else {
      #pragma unroll
      for (int nt = 0; nt < 4; ++nt)
        #pragma unroll
        for (int rg = 0; rg < 4; ++rg){
          int i = qrb + g*4 + rg;
          int j = j0 + nt*16 + l15;
          bool ok = (j <= i) || ((i < p) && (j < p));
          float sv = ok ? sa[nt][rg] : -3e38f;
          sa[nt][rg] = sv;
          tm[rg] = fmaxf(tm[rg], sv);
        }
    }
    #pragma unroll
    for (int mk = 1; mk <= 8; mk <<= 1)
      #pragma unroll
      for (int rg = 0; rg < 4; ++rg) tm[rg] = fmaxf(tm[rg], __shfl_xor(tm[rg], mk));
    // online softmax update
    float sf[4];
    #pragma unroll
    for (int rg = 0; rg < 4; ++rg){
      float nm = fmaxf(mr[rg], tm[rg]);
      sf[rg] = __expf(mr[rg] - nm);
      mr[rg] = nm;
    }
    #pragma unroll
    for (int dt = 0; dt < 8; ++dt)
      #pragma unroll
      for (int rg = 0; rg < 4; ++rg) O[dt][rg] *= sf[rg];
    float rs[4] = {0.f,0.f,0.f,0.f};
    #pragma unroll
    for (int nt = 0; nt < 4; ++nt)
      #pragma unroll
      for (int rg = 0; rg < 4; ++rg){
        float e = __expf(sa[nt][rg] - mr[rg]);
        sa[nt][rg] = e;
        rs[rg] += e;
      }
    #pragma unroll
    for (int mk = 1; mk <= 8; mk <<= 1)
      #pragma unroll
      for (int rg = 0; rg < 4; ++rg) rs[rg] += __shfl_xor(rs[rg], mk);
    #pragma unroll
    for (int rg = 0; rg < 4; ++rg) lr[rg] = lr[rg]*sf[rg] + rs[rg];
    // P -> per-wave private LDS (stride 68), no barrier needed (in-wave DS ordering)
    unsigned short* ps = &Ps[wave][0];
    #pragma unroll
    for (int nt = 0; nt < 4; ++nt)
      #pragma unroll
      for (int rg = 0; rg < 4; ++rg)
        ps[(g*4+rg)*68 + nt*16 + l15] = f2bf(sa[nt][rg]);
    s16x8 pf[2];
    #pragma unroll
    for (int kc = 0; kc < 2; ++kc) pf[kc] = *(const s16x8*)(ps + l15*68 + kc*32 + g*8);
    // PV from prefetched registers
    __builtin_amdgcn_s_setprio(1);
    #pragma unroll
    for (int dt = 0; dt < 8; ++dt)
      #pragma unroll
      for (int kc = 0; kc < 2; ++kc)
        O[dt] = __builtin_amdgcn_mfma_f32_16x16x32_bf16(pf[kc], vf[dt][kc], O[dt], 0, 0, 0);
    __builtin_amdgcn_s_setprio(0);
    __syncthreads();   // drains next-tile stage (vmcnt) + frees Ks[cur] for restage
    cur ^= 1;
  }
  float inv[4];
  #pragma unroll
  for (int rg = 0; rg < 4; ++rg) inv[rg] = 1.0f / lr[rg];
  #pragma unroll
  for (int dt = 0; dt < 8; ++dt)
    #pragma unroll
    for (int rg = 0; rg < 4; ++rg){
      int row = qrb + g*4 + rg;
      int col = h*128 + dt*16 + l15;
      attn_out[(long)(b*S_LEN + row)*DIMM + col] = f2bf(O[dt][rg]*inv[rg]);
    }
}

extern "C" void kernel_launch(void* const* d_in, const int* in_sizes, int n_in,
                              void* d_out, int out_size, void* d_ws, size_t ws_size,
                              hipStream_t stream){
  const float* x    = (const float*)d_in[0];
  const float* cosb = (const float*)d_in[1];
  const float* sinb = (const float*)d_in[2];
  const float* wq   = (const float*)d_in[3];
  const float* wk   = (const float*)d_in[4];
  const float* wv   = (const float*)d_in[5];
  const float* wo   = (const float*)d_in[6];
  const float* qg   = (const float*)d_in[7];
  const float* kg   = (const float*)d_in[8];
  const int*   pp   = (const int*)d_in[9];

  char* ws = (char*)d_ws;
  unsigned short* xb    = (unsigned short*)(ws);                 // 4096x2048 bf16
  unsigned short* wqkvb = (unsigned short*)(ws + 16777216);      // 2560x2048 bf16
  unsigned short* wob   = (unsigned short*)(ws + 27262976);      // 2048x2048 bf16
  float*          qkv   = (float*)(ws + 35651584);               // 4096x2560 f32
  unsigned short* qat   = (unsigned short*)(ws + 77594624);      // [B,16,S,128]
  unsigned short* kat   = (unsigned short*)(ws + 94371840);      // [B,2,S,128]
  unsigned short* vt    = (unsigned short*)(ws + 96468992);      // [B,2,128,S]
  unsigned short* aout  = (unsigned short*)(ws + 98566144);      // [B,S,2048]

  cvt_bf16<<<8388608/2048, 256, 0, stream>>>(x,  xb, 8388608);
  cvt_bf16<<<4194304/2048, 256, 0, stream>>>(wq, wqkvb, 4194304);
  cvt_bf16<<< 524288/2048, 256, 0, stream>>>(wk, wqkvb + 4194304, 524288);
  cvt_bf16<<< 524288/2048, 256, 0, stream>>>(wv, wqkvb + 4718592, 524288);
  cvt_bf16<<<4194304/2048, 256, 0, stream>>>(wo, wob, 4194304);

  gemm_bt<<<dim3(2560/128, 4096/128), 256, 0, stream>>>(xb, wqkvb, qkv, 4096, 2560, 2048);
  normrope<<<73728/4, 256, 0, stream>>>(qkv, cosb, sinb, qg, kg, qat, kat);
  vtrans<<<128, 256, 0, stream>>>(qkv, vt);
  attn_fwd<<<1024, 256, 0, stream>>>(qat, kat, vt, aout, pp);
  gemm_bt<<<dim3(2048/128, 4096/128), 256, 0, stream>>>(aout, wob, (float*)d_out, 4096, 2048, 2048);
}

// Round 4
// 298.880 us; speedup vs baseline: 1.1557x; 1.0208x over previous
//
#include <hip/hip_runtime.h>
#include <stdint.h>

#define S_LEN 2048
#define DIMM  2048
#define NH    16
#define NKV   2

typedef __attribute__((ext_vector_type(8))) short s16x8;
typedef __attribute__((ext_vector_type(8))) unsigned short u16x8;
typedef __attribute__((ext_vector_type(4))) float f32x4;
typedef __attribute__((ext_vector_type(4))) unsigned int u32x4;

__device__ __forceinline__ unsigned short f2bf(float f){
  unsigned int u = __builtin_bit_cast(unsigned int, f);
  u += 0x7fffu + ((u >> 16) & 1u);
  return (unsigned short)(u >> 16);
}

__device__ __forceinline__ void gload16(const void* g, void* l){
  __builtin_amdgcn_global_load_lds(
      (const __attribute__((address_space(1))) unsigned int*)g,
      (__attribute__((address_space(3))) unsigned int*)l, 16, 0, 0);
}

// ---------------- fp32 -> bf16 convert ----------------
__global__ __launch_bounds__(256) void cvt_bf16(const float* __restrict__ src,
                                                unsigned short* __restrict__ dst, int n){
  int i = (blockIdx.x * 256 + threadIdx.x) * 8;
  if (i >= n) return;
  const float4* s4 = (const float4*)(src + i);
  float4 a = s4[0], b = s4[1];
  u16x8 o;
  o[0]=f2bf(a.x); o[1]=f2bf(a.y); o[2]=f2bf(a.z); o[3]=f2bf(a.w);
  o[4]=f2bf(b.x); o[5]=f2bf(b.y); o[6]=f2bf(b.z); o[7]=f2bf(b.w);
  *(u16x8*)(dst + i) = o;
}

// ---------------- C = A(bf16,[M,K]) @ W(bf16,[N,K])^T -> fp32 [M,N] ----------------
__global__ __launch_bounds__(256) void gemm_bt(const unsigned short* __restrict__ A,
                                               const unsigned short* __restrict__ W,
                                               float* __restrict__ C,
                                               int M, int N, int K){
  __shared__ __attribute__((aligned(16))) unsigned short As[128*64];
  __shared__ __attribute__((aligned(16))) unsigned short Bs[128*64];
  const int t = threadIdx.x;
  const int lane = t & 63, wave = t >> 6;
  const int l15 = lane & 15, g = lane >> 4;
  const int m0 = blockIdx.y * 128, n0 = blockIdx.x * 128;
  const int wm = (wave >> 1) * 64, wn = (wave & 1) * 64;
  const int srow = t >> 3, sdblk = t & 7;
  const long ldsoff = (long)(t >> 6) * 1024;
  f32x4 acc[4][4] = {};
  for (int k0 = 0; k0 < K; k0 += 64){
    __syncthreads();
    #pragma unroll
    for (int r = 0; r < 4; ++r){
      int row = r*32 + srow;
      int db  = sdblk ^ (row & 7);
      gload16(A + (long)(m0+row)*K + k0 + db*8, (char*)As + r*4096 + ldsoff);
    }
    #pragma unroll
    for (int r = 0; r < 4; ++r){
      int row = r*32 + srow;
      int db  = sdblk ^ (row & 7);
      gload16(W + (long)(n0+row)*K + k0 + db*8, (char*)Bs + r*4096 + ldsoff);
    }
    __syncthreads();
    s16x8 af[4][2], bfr[4][2];
    #pragma unroll
    for (int mi = 0; mi < 4; ++mi)
      #pragma unroll
      for (int kc = 0; kc < 2; ++kc){
        int row = wm + mi*16 + l15;
        int db = (kc*4 + g) ^ (row & 7);
        af[mi][kc] = *(const s16x8*)(As + row*64 + db*8);
      }
    #pragma unroll
    for (int ni = 0; ni < 4; ++ni)
      #pragma unroll
      for (int kc = 0; kc < 2; ++kc){
        int row = wn + ni*16 + l15;
        int db = (kc*4 + g) ^ (row & 7);
        bfr[ni][kc] = *(const s16x8*)(Bs + row*64 + db*8);
      }
    #pragma unroll
    for (int mi = 0; mi < 4; ++mi)
      #pragma unroll
      for (int ni = 0; ni < 4; ++ni)
        #pragma unroll
        for (int kc = 0; kc < 2; ++kc)
          acc[mi][ni] = __builtin_amdgcn_mfma_f32_16x16x32_bf16(af[mi][kc], bfr[ni][kc], acc[mi][ni], 0, 0, 0);
  }
  #pragma unroll
  for (int mi = 0; mi < 4; ++mi)
    #pragma unroll
    for (int ni = 0; ni < 4; ++ni)
      #pragma unroll
      for (int rg = 0; rg < 4; ++rg){
        int row = m0 + wm + mi*16 + g*4 + rg;
        int col = n0 + wn + ni*16 + l15;
        C[(long)row*N + col] = acc[mi][ni][rg];
      }
}

// ---------------- RMSNorm + rotary for Q and K ----------------
// Q gets (1/sqrt(128))*log2(e) folded in => attention exp becomes exp2.
__global__ __launch_bounds__(256) void normrope(const float* __restrict__ qkv,
    const float* __restrict__ cosb, const float* __restrict__ sinb,
    const float* __restrict__ qg, const float* __restrict__ kg,
    unsigned short* __restrict__ q_attn, unsigned short* __restrict__ k_attn){
  int wave = threadIdx.x >> 6, lane = threadIdx.x & 63;
  int rid = blockIdx.x * 4 + wave;
  int d0 = lane * 2;
  const float* src; unsigned short* dst; const float* gm; float sc; int s;
  if (rid < 2*S_LEN*NH){
    int bs = rid >> 4, h = rid & 15;
    int b = bs >> 11; s = bs & 2047;
    src = qkv + (long)bs*2560 + h*128;
    dst = q_attn + ((long)(b*NH + h)*S_LEN + s)*128;
    gm = qg; sc = 0.08838834764831845f * 1.4426950408889634f;  // scale * log2(e)
  } else {
    int r2 = rid - 2*S_LEN*NH;
    int bs = r2 >> 1, kv = r2 & 1;
    int b = bs >> 11; s = bs & 2047;
    src = qkv + (long)bs*2560 + 2048 + kv*128;
    dst = k_attn + ((long)(b*NKV + kv)*S_LEN + s)*128;
    gm = kg; sc = 1.0f;
  }
  float2 x = *(const float2*)(src + d0);
  float ss = x.x*x.x + x.y*x.y;
  #pragma unroll
  for (int m = 1; m < 64; m <<= 1) ss += __shfl_xor(ss, m);
  float r = rsqrtf(ss * (1.0f/128.0f) + 1e-6f);
  float2 gv = *(const float2*)(gm + d0);
  float n0 = x.x * r * gv.x, n1 = x.y * r * gv.y;
  float p0 = __shfl_xor(n0, 32), p1 = __shfl_xor(n1, 32);
  float sgn = (d0 < 64) ? -1.f : 1.f;
  float2 c  = *(const float2*)(cosb + (long)s*128 + d0);
  float2 sn = *(const float2*)(sinb + (long)s*128 + d0);
  float o0 = (n0*c.x + sgn*p0*sn.x) * sc;
  float o1 = (n1*c.y + sgn*p1*sn.y) * sc;
  unsigned int pk = (unsigned int)f2bf(o0) | ((unsigned int)f2bf(o1) << 16);
  *(unsigned int*)(dst + d0) = pk;
}

// ---------------- V: [B,S,KV,128] cols of qkv -> bf16 [B,KV,128,S] (transposed) ----------------
__global__ __launch_bounds__(256) void vtrans(const float* __restrict__ qkv,
                                              unsigned short* __restrict__ v_t){
  __shared__ __attribute__((aligned(16))) unsigned short lds[128*72];
  int bid = blockIdx.x;
  int s0 = (bid & 31) * 64;
  int kv = (bid >> 5) & 1;
  int b  = bid >> 6;
  int t = threadIdx.x;
  #pragma unroll
  for (int it = 0; it < 32; ++it){
    int idx = it*256 + t;
    int s = idx >> 7, d = idx & 127;
    float v = qkv[(long)(b*S_LEN + s0 + s)*2560 + 2304 + kv*128 + d];
    lds[d*72 + s] = f2bf(v);
  }
  __syncthreads();
  #pragma unroll
  for (int it = 0; it < 4; ++it){
    int c = it*256 + t;
    int d = c >> 3, s8 = c & 7;
    u16x8 vv = *(const u16x8*)(lds + d*72 + s8*8);
    *(u16x8*)(v_t + ((long)(b*NKV + kv)*128 + d)*S_LEN + s0 + s8*8) = vv;
  }
}

// ---------------- flash attention (swapped-QK^T: q-row is lane-local) ----------------
// grid: 32(qt, LPT desc) x 32(b,h); block 256 = 4 waves x 16 q-rows. KVB=64.
// mfma(K,Q) => lane (g,l15) holds S[q=l15][k=nt*16+g*4+rg]; softmax stats are
// 1 scalar/lane + 2 shuffles. P->bf16 via v_cvt_pk + in-register shfl exchange.
__global__ __launch_bounds__(256) void attn_fwd(const unsigned short* __restrict__ q_attn,
    const unsigned short* __restrict__ k_attn, const unsigned short* __restrict__ v_t,
    unsigned short* __restrict__ attn_out, const int* __restrict__ pp){
  __shared__ __attribute__((aligned(16))) unsigned short Ks[2][64*128];
  const int p = pp[0];
  int bid = blockIdx.x;
  int qt = 31 - (bid >> 5);          // LPT: longest blocks dispatch first
  int bh = bid & 31;
  int h = bh & 15, b = bh >> 4;
  int kvh = h >> 3;
  int t = threadIdx.x, wave = t >> 6, lane = t & 63;
  int l15 = lane & 15, g = lane >> 4;
  int qs = qt * 64;
  int qrb = qs + wave*16;
  const unsigned short* qb = q_attn + ((long)(b*NH + h)*S_LEN + qrb + l15)*128;
  s16x8 qf[4];
  #pragma unroll
  for (int kc = 0; kc < 4; ++kc) qf[kc] = *(const s16x8*)(qb + g*8 + kc*32);
  f32x4 O[8] = {};
  float mr = -3e38f, lr = 0.f;       // stats for q-row (qrb + l15), one per lane
  int kv_end = (qs < p) ? ((p > qs+64) ? p : qs+64) : (qs+64);
  const unsigned short* kb0 = k_attn + ((long)(b*NKV + kvh)*S_LEN)*128;
  const unsigned short* vb0 = v_t + ((long)(b*NKV + kvh)*128)*S_LEN;
  const int srow16 = t >> 4, sd16 = t & 15;
  const long ldsoff = (long)wave * 1024;
  const unsigned short* vbase = vb0 + (long)l15*S_LEN + g*8;
  const int iv = qrb + l15;          // this lane's q-row

  // prologue: stage tile 0 into Ks[0]
  #pragma unroll
  for (int r = 0; r < 4; ++r){
    int j = r*16 + srow16;
    int db = sd16 ^ (j & 7);
    gload16(kb0 + (long)j*128 + db*8, (char*)Ks[0] + r*4096 + ldsoff);
  }
  __syncthreads();
  int cur = 0;

  for (int j0 = 0; j0 < kv_end; j0 += 64){
    // V prefetch batch A (dt 0..3) into registers
    s16x8 vfA[4][2];
    #pragma unroll
    for (int dt = 0; dt < 4; ++dt)
      #pragma unroll
      for (int kc = 0; kc < 2; ++kc)
        vfA[dt][kc] = *(const s16x8*)(vbase + (long)dt*16*S_LEN + j0 + kc*32);
    // stage NEXT K tile (drains at the bottom barrier)
    if (j0 + 64 < kv_end){
      const unsigned short* kb = kb0 + (long)(j0 + 64)*128;
      char* dst = (char*)Ks[cur^1] + ldsoff;
      #pragma unroll
      for (int r = 0; r < 4; ++r){
        int j = r*16 + srow16;
        int db = sd16 ^ (j & 7);
        gload16(kb + (long)j*128 + db*8, dst + r*4096);
      }
    }
    // swapped QK^T: sa[nt] = K_frag * Q_frag  => S^T tile
    const unsigned short* ksc = Ks[cur];
    f32x4 sa[4] = {};
    __builtin_amdgcn_s_setprio(1);
    #pragma unroll
    for (int nt = 0; nt < 4; ++nt){
      int krow = nt*16 + l15;
      #pragma unroll
      for (int kc = 0; kc < 4; ++kc){
        int db = (kc*4 + g) ^ (krow & 7);
        s16x8 kf = *(const s16x8*)(ksc + krow*128 + db*8);
        sa[nt] = __builtin_amdgcn_mfma_f32_16x16x32_bf16(kf, qf[kc], sa[nt], 0, 0, 0);
      }
    }
    __builtin_amdgcn_s_setprio(0);
    // V prefetch batch B (dt 4..7) — lands during softmax
    s16x8 vfB[4][2];
    #pragma unroll
    for (int dt = 0; dt < 4; ++dt)
      #pragma unroll
      for (int kc = 0; kc < 2; ++kc)
        vfB[dt][kc] = *(const s16x8*)(vbase + (long)(dt+4)*16*S_LEN + j0 + kc*32);
    // mask + in-lane row max (all 16 values belong to q-row iv)
    float tm = -3e38f;
    bool full = (j0 + 63 <= qrb) || ((qrb + 15 < p) && (j0 + 63 < p));
    if (full){
      #pragma unroll
      for (int nt = 0; nt < 4; ++nt)
        #pragma unroll
        for (int rg = 0; rg < 4; ++rg) tm = fmaxf(tm, sa[nt][rg]);
    } else {
      #pragma unroll
      for (int nt = 0; nt < 4; ++nt)
        #pragma unroll
        for (int rg = 0; rg < 4; ++rg){
          int j = j0 + nt*16 + g*4 + rg;
          bool ok = (j <= iv) || ((iv < p) && (j < p));
          float sv = ok ? sa[nt][rg] : -3e38f;
          sa[nt][rg] = sv;
          tm = fmaxf(tm, sv);
        }
    }
    tm = fmaxf(tm, __shfl_xor(tm, 16));
    tm = fmaxf(tm, __shfl_xor(tm, 32));
    // online softmax (log2 domain; scale*log2e pre-folded into Q)
    if (!__all(tm <= mr + 8.0f)){       // T13 defer-max: rescale only on real growth
      float nm = fmaxf(mr, tm);
      float sfv = exp2f(mr - nm);
      mr = nm;
      lr *= sfv;
      float sfO[4];
      #pragma unroll
      for (int rg = 0; rg < 4; ++rg)
        sfO[rg] = __shfl(sfv, (lane & 48) | (g*4 + rg));
      #pragma unroll
      for (int dt = 0; dt < 8; ++dt)
        #pragma unroll
        for (int rg = 0; rg < 4; ++rg) O[dt][rg] *= sfO[rg];
    }
    float rs = 0.f;
    #pragma unroll
    for (int nt = 0; nt < 4; ++nt)
      #pragma unroll
      for (int rg = 0; rg < 4; ++rg){
        float e = exp2f(sa[nt][rg] - mr);
        sa[nt][rg] = e;
        rs += e;
      }
    rs += __shfl_xor(rs, 16);
    rs += __shfl_xor(rs, 32);
    lr += rs;
    // pack P rows to bf16 pairs: u[nt][h] = (P[k=nt*16+g*4+2h], P[..+2h+1])
    unsigned int u[4][2];
    #pragma unroll
    for (int nt = 0; nt < 4; ++nt)
      #pragma unroll
      for (int hh = 0; hh < 2; ++hh){
        float lo = sa[nt][2*hh], hi = sa[nt][2*hh+1];
        unsigned int r;
        asm("v_cvt_pk_bf16_f32 %0, %1, %2" : "=v"(r) : "v"(lo), "v"(hi));
        u[nt][hh] = r;
      }
    // redistribute into PV A-fragments: w[j] = u[2kc+(g>>1)][j&1] from lane ((2g+(j>>1))&3,l15)
    s16x8 pf[2];
    #pragma unroll
    for (int kc = 0; kc < 2; ++kc){
      u32x4 w;
      #pragma unroll
      for (int j = 0; j < 4; ++j){
        int srcl = (((2*g + (j>>1)) & 3) << 4) | l15;
        int va = __shfl((int)u[2*kc][j&1],   srcl);
        int vb = __shfl((int)u[2*kc+1][j&1], srcl);
        w[j] = (unsigned int)((g & 2) ? vb : va);
      }
      pf[kc] = __builtin_bit_cast(s16x8, w);
    }
    // PV from prefetched registers
    __builtin_amdgcn_s_setprio(1);
    #pragma unroll
    for (int dt = 0; dt < 4; ++dt)
      #pragma unroll
      for (int kc = 0; kc < 2; ++kc)
        O[dt] = __builtin_amdgcn_mfma_f32_16x16x32_bf16(pf[kc], vfA[dt][kc], O[dt], 0, 0, 0);
    #pragma unroll
    for (int dt = 4; dt < 8; ++dt)
      #pragma unroll
      for (int kc = 0; kc < 2; ++kc)
        O[dt] = __builtin_amdgcn_mfma_f32_16x16x32_bf16(pf[kc], vfB[dt-4][kc], O[dt], 0, 0, 0);
    __builtin_amdgcn_s_setprio(0);
    __syncthreads();   // drains next-tile stage + frees Ks[cur]
    cur ^= 1;
  }
  // epilogue: redistribute 1/lr from l15-domain to O-domain
  float inv = 1.0f / lr;
  float invO[4];
  #pragma unroll
  for (int rg = 0; rg < 4; ++rg)
    invO[rg] = __shfl(inv, (lane & 48) | (g*4 + rg));
  #pragma unroll
  for (int dt = 0; dt < 8; ++dt)
    #pragma unroll
    for (int rg = 0; rg < 4; ++rg){
      int row = qrb + g*4 + rg;
      int col = h*128 + dt*16 + l15;
      attn_out[(long)(b*S_LEN + row)*DIMM + col] = f2bf(O[dt][rg]*invO[rg]);
    }
}

extern "C" void kernel_launch(void* const* d_in, const int* in_sizes, int n_in,
                              void* d_out, int out_size, void* d_ws, size_t ws_size,
                              hipStream_t stream){
  const float* x    = (const float*)d_in[0];
  const float* cosb = (const float*)d_in[1];
  const float* sinb = (const float*)d_in[2];
  const float* wq   = (const float*)d_in[3];
  const float* wk   = (const float*)d_in[4];
  const float* wv   = (const float*)d_in[5];
  const float* wo   = (const float*)d_in[6];
  const float* qg   = (const float*)d_in[7];
  const float* kg   = (const float*)d_in[8];
  const int*   pp   = (const int*)d_in[9];

  char* ws = (char*)d_ws;
  unsigned short* xb    = (unsigned short*)(ws);                 // 4096x2048 bf16
  unsigned short* wqkvb = (unsigned short*)(ws + 16777216);      // 2560x2048 bf16
  unsigned short* wob   = (unsigned short*)(ws + 27262976);      // 2048x2048 bf16
  float*          qkv   = (float*)(ws + 35651584);               // 4096x2560 f32
  unsigned short* qat   = (unsigned short*)(ws + 77594624);      // [B,16,S,128]
  unsigned short* kat   = (unsigned short*)(ws + 94371840);      // [B,2,S,128]
  unsigned short* vt    = (unsigned short*)(ws + 96468992);      // [B,2,128,S]
  unsigned short* aout  = (unsigned short*)(ws + 98566144);      // [B,S,2048]

  cvt_bf16<<<8388608/2048, 256, 0, stream>>>(x,  xb, 8388608);
  cvt_bf16<<<4194304/2048, 256, 0, stream>>>(wq, wqkvb, 4194304);
  cvt_bf16<<< 524288/2048, 256, 0, stream>>>(wk, wqkvb + 4194304, 524288);
  cvt_bf16<<< 524288/2048, 256, 0, stream>>>(wv, wqkvb + 4718592, 524288);
  cvt_bf16<<<4194304/2048, 256, 0, stream>>>(wo, wob, 4194304);

  gemm_bt<<<dim3(2560/128, 4096/128), 256, 0, stream>>>(xb, wqkvb, qkv, 4096, 2560, 2048);
  normrope<<<73728/4, 256, 0, stream>>>(qkv, cosb, sinb, qg, kg, qat, kat);
  vtrans<<<128, 256, 0, stream>>>(qkv, vt);
  attn_fwd<<<1024, 256, 0, stream>>>(qat, kat, vt, aout, pp);
  gemm_bt<<<dim3(2048/128, 4096/128), 256, 0, stream>>>(aout, wob, (float*)d_out, 4096, 2048, 2048);
}